// Round 1
// baseline (274.320 us; speedup 1.0000x reference)
//
#include <hip/hip_runtime.h>
#include <math.h>

#define BB 2
#define SS 192
#define DD 512
#define HH 8
#define HD 64
#define QC 12            // q-rows per block in main kernel
#define PROJ_N (BB*HH*SS*HD)   // 196608 elements per projected tensor

// ---------------------------------------------------------------------------
// Tiled f32 GEMM body: y = x @ W^T   (x: M x 512 row-major, W: 512 x 512)
// y[n,j] = sum_i x[n,i] * W[j,i]
// SPLIT=1: scatter into head-split layout [(b*H + j/64)*S + s]*64 + (j%64)
// SPLIT=0: plain row-major y[n*512 + j]
// ---------------------------------------------------------------------------
template <int SPLIT>
__device__ __forceinline__ void gemm_body(const float* __restrict__ x,
                                          const float* __restrict__ W,
                                          float* __restrict__ y) {
    __shared__ float As[32][68];  // As[i][m] : x tile transposed (pad 68 -> 16B-aligned rows)
    __shared__ float Bs[32][68];  // Bs[i][n] : W^T tile

    const int t  = threadIdx.x;
    const int tx = t & 15;        // 0..15 -> n micro
    const int ty = t >> 4;        // 0..15 -> m micro
    const int m0 = blockIdx.x * 64;
    const int n0 = blockIdx.y * 64;

    float acc[4][4];
#pragma unroll
    for (int a = 0; a < 4; ++a)
#pragma unroll
        for (int b = 0; b < 4; ++b) acc[a][b] = 0.f;

    for (int kk = 0; kk < 512; kk += 32) {
#pragma unroll
        for (int r = 0; r < 2; ++r) {
            const int id  = t + r * 256;   // 0..511
            const int row = id >> 3;       // 0..63
            const int i4  = (id & 7) * 4;  // 0..28
            const float4 av = *reinterpret_cast<const float4*>(&x[(m0 + row) * 512 + kk + i4]);
            As[i4 + 0][row] = av.x; As[i4 + 1][row] = av.y;
            As[i4 + 2][row] = av.z; As[i4 + 3][row] = av.w;
            const float4 bv = *reinterpret_cast<const float4*>(&W[(n0 + row) * 512 + kk + i4]);
            Bs[i4 + 0][row] = bv.x; Bs[i4 + 1][row] = bv.y;
            Bs[i4 + 2][row] = bv.z; Bs[i4 + 3][row] = bv.w;
        }
        __syncthreads();
#pragma unroll
        for (int i = 0; i < 32; ++i) {
            const float4 a4 = *reinterpret_cast<const float4*>(&As[i][ty * 4]);
            const float4 b4 = *reinterpret_cast<const float4*>(&Bs[i][tx * 4]);
            const float a[4] = {a4.x, a4.y, a4.z, a4.w};
            const float b[4] = {b4.x, b4.y, b4.z, b4.w};
#pragma unroll
            for (int mi = 0; mi < 4; ++mi)
#pragma unroll
                for (int ni = 0; ni < 4; ++ni)
                    acc[mi][ni] = fmaf(a[mi], b[ni], acc[mi][ni]);
        }
        __syncthreads();
    }

#pragma unroll
    for (int mi = 0; mi < 4; ++mi) {
        const int n_row = m0 + ty * 4 + mi;  // = b*S + s
#pragma unroll
        for (int ni = 0; ni < 4; ++ni) {
            const int j = n0 + tx * 4 + ni;
            const float v = acc[mi][ni];
            if (SPLIT) {
                const int b = n_row / SS, s = n_row % SS;
                const int h = j >> 6, e = j & 63;
                y[((b * HH + h) * SS + s) * HD + e] = v;
            } else {
                y[n_row * 512 + j] = v;
            }
        }
    }
}

// Fused 4-way projection: p=0 q@Wq, p=1 k@Wk, p=2 l@Wk (faithful!), p=3 v@Wv
__global__ __launch_bounds__(256) void proj4_kernel(
    const float* __restrict__ xq, const float* __restrict__ xk,
    const float* __restrict__ xl, const float* __restrict__ xv,
    const float* __restrict__ Wq, const float* __restrict__ Wk,
    const float* __restrict__ Wv, float* __restrict__ ws) {
    const int p = blockIdx.z;
    const float* x = (p == 0) ? xq : (p == 1) ? xk : (p == 2) ? xl : xv;
    const float* W = (p == 0) ? Wq : (p == 3) ? Wv : Wk;
    float* y = ws + p * PROJ_N;
    gemm_body<1>(x, W, y);
}

__global__ __launch_bounds__(256) void outproj_kernel(
    const float* __restrict__ att, const float* __restrict__ Wout,
    float* __restrict__ out) {
    gemm_body<0>(att, Wout, out);
}

// ---------------------------------------------------------------------------
// Main rank-3 attention kernel.
// Grid: 256 blocks = (b,h) x 16 q-chunks (QC=12). Block: 512 threads.
// Per block: stage kh, lh transposed (e-major) in LDS; per q: 192x192 scores
// tiled 12k x 6l per thread over a 16x16 thread grid; per-k online softmax
// stats; exact joint (k,l) softmax combine; attended = sum_k w[k]*vh[k,:].
// ---------------------------------------------------------------------------
__global__ __launch_bounds__(512) void attn3d_kernel(
    const float* __restrict__ qh, const float* __restrict__ kh,
    const float* __restrict__ lh, const float* __restrict__ vh,
    float* __restrict__ att) {
    __shared__ float kt[64][196];   // kt[e][k]  (pad 196: 16B-aligned rows)
    __shared__ float lt[64][196];   // lt[e][l]
    __shared__ float qs[QC][64];    // qh rows, pre-scaled by 1/8
    __shared__ float mr[2][SS];     // per-k rowmax / rowsum-exp
    __shared__ float wk[SS];        // per-k softmax weight
    __shared__ float part[8][64];   // attended partials

    const int blk = blockIdx.x;
    const int qc  = blk & 15;       // 16 q-chunks
    const int bh  = blk >> 4;       // 0..15
    const int t   = threadIdx.x;
    const int tl  = t & 31;         // 0..31 -> l groups
    const int tk  = t >> 5;         // 0..15 -> k groups

    const float* khp = kh + bh * SS * HD;
    const float* lhp = lh + bh * SS * HD;

    // Stage transposed K/L tiles (coalesced global reads).
    for (int id = t; id < SS * HD; id += 512) {
        const int k = id >> 6, e = id & 63;
        kt[e][k] = khp[id];
        lt[e][k] = lhp[id];
    }
    // Stage q rows with 1/sqrt(hd) folded in.
    for (int id = t; id < QC * HD; id += 512) {
        const int qi = id >> 6, e = id & 63;
        qs[qi][e] = qh[(bh * SS + qc * QC + qi) * HD + e] * 0.125f;
    }
    __syncthreads();

    const int kbase = tk * 12;
    const int lbase = tl * 6;

    for (int qi = 0; qi < QC; ++qi) {
        float acc[12][6];
#pragma unroll
        for (int a = 0; a < 12; ++a)
#pragma unroll
            for (int b = 0; b < 6; ++b) acc[a][b] = 0.f;

#pragma unroll 2
        for (int e = 0; e < 64; ++e) {
            const float qv = qs[qi][e];
            const float4 k0 = *reinterpret_cast<const float4*>(&kt[e][kbase]);
            const float4 k1 = *reinterpret_cast<const float4*>(&kt[e][kbase + 4]);
            const float4 k2 = *reinterpret_cast<const float4*>(&kt[e][kbase + 8]);
            const float2 l0 = *reinterpret_cast<const float2*>(&lt[e][lbase]);
            const float2 l1 = *reinterpret_cast<const float2*>(&lt[e][lbase + 2]);
            const float2 l2 = *reinterpret_cast<const float2*>(&lt[e][lbase + 4]);
            const float g[12] = {qv * k0.x, qv * k0.y, qv * k0.z, qv * k0.w,
                                 qv * k1.x, qv * k1.y, qv * k1.z, qv * k1.w,
                                 qv * k2.x, qv * k2.y, qv * k2.z, qv * k2.w};
            const float lv[6] = {l0.x, l0.y, l1.x, l1.y, l2.x, l2.y};
#pragma unroll
            for (int a = 0; a < 12; ++a)
#pragma unroll
                for (int b = 0; b < 6; ++b)
                    acc[a][b] = fmaf(g[a], lv[b], acc[a][b]);
        }

        // Per-k row stats over l (32 lanes per k-row share the same tk).
        float m_loc[12], r_loc[12];
#pragma unroll
        for (int a = 0; a < 12; ++a) {
            float m = acc[a][0];
#pragma unroll
            for (int b = 1; b < 6; ++b) m = fmaxf(m, acc[a][b]);
#pragma unroll
            for (int off = 16; off >= 1; off >>= 1)
                m = fmaxf(m, __shfl_xor(m, off, 64));
            float r = 0.f;
#pragma unroll
            for (int b = 0; b < 6; ++b) r += __expf(acc[a][b] - m);
#pragma unroll
            for (int off = 16; off >= 1; off >>= 1)
                r += __shfl_xor(r, off, 64);
            m_loc[a] = m;
            r_loc[a] = r;
        }
        if (tl == 0) {
#pragma unroll
            for (int a = 0; a < 12; ++a) {
                mr[0][kbase + a] = m_loc[a];
                mr[1][kbase + a] = r_loc[a];
            }
        }
        __syncthreads();

        // Joint (k,l) softmax combine on wave 0.
        if (t < 64) {
            float m3[3], r3[3];
#pragma unroll
            for (int j = 0; j < 3; ++j) {
                m3[j] = mr[0][t + 64 * j];
                r3[j] = mr[1][t + 64 * j];
            }
            float M = fmaxf(m3[0], fmaxf(m3[1], m3[2]));
#pragma unroll
            for (int off = 32; off >= 1; off >>= 1)
                M = fmaxf(M, __shfl_xor(M, off, 64));
            float z = r3[0] * __expf(m3[0] - M) + r3[1] * __expf(m3[1] - M) +
                      r3[2] * __expf(m3[2] - M);
#pragma unroll
            for (int off = 32; off >= 1; off >>= 1)
                z += __shfl_xor(z, off, 64);
            const float invZ = 1.f / z;
#pragma unroll
            for (int j = 0; j < 3; ++j)
                wk[t + 64 * j] = r3[j] * __expf(m3[j] - M) * invZ;
        }
        __syncthreads();

        // attended[d] = sum_k wk[k] * vh[k,d]
        {
            const int kg = t >> 6, d = t & 63;
            const float* vp = vh + (bh * SS + kg * 24) * HD + d;
            float p = 0.f;
#pragma unroll
            for (int j = 0; j < 24; ++j) p = fmaf(wk[kg * 24 + j], vp[j * HD], p);
            part[kg][d] = p;
        }
        __syncthreads();
        if (t < 64) {
            float p = 0.f;
#pragma unroll
            for (int j = 0; j < 8; ++j) p += part[j][t];
            const int b = bh / HH, h = bh % HH;
            const int s = qc * QC + qi;
            att[(b * SS + s) * DD + h * HD + t] = p;
        }
        __syncthreads();
    }
}

extern "C" void kernel_launch(void* const* d_in, const int* in_sizes, int n_in,
                              void* d_out, int out_size, void* d_ws, size_t ws_size,
                              hipStream_t stream) {
    (void)in_sizes; (void)n_in; (void)out_size; (void)ws_size;
    const float* q    = (const float*)d_in[0];
    const float* k    = (const float*)d_in[1];
    const float* l    = (const float*)d_in[2];
    const float* v    = (const float*)d_in[3];
    const float* Wq   = (const float*)d_in[4];
    const float* Wk   = (const float*)d_in[5];
    const float* Wv   = (const float*)d_in[6];
    const float* Wout = (const float*)d_in[7];
    float* out = (float*)d_out;

    float* ws  = (float*)d_ws;
    float* qhp = ws + 0 * PROJ_N;
    float* khp = ws + 1 * PROJ_N;
    float* lhp = ws + 2 * PROJ_N;
    float* vhp = ws + 3 * PROJ_N;
    float* atp = ws + 4 * PROJ_N;

    // 1) all four head projections (l uses Wk, faithful to reference)
    proj4_kernel<<<dim3(384 / 64, 512 / 64, 4), 256, 0, stream>>>(
        q, k, l, v, Wq, Wk, Wv, ws);
    // 2) rank-3 attention + joint softmax + value contraction
    attn3d_kernel<<<dim3(256), 512, 0, stream>>>(qhp, khp, lhp, vhp, atp);
    // 3) output projection
    outproj_kernel<<<dim3(384 / 64, 512 / 64), 256, 0, stream>>>(atp, Wout, out);
}

// Round 2
// 127.569 us; speedup vs baseline: 2.1504x; 2.1504x over previous
//
#include <hip/hip_runtime.h>
#include <math.h>

#define BB 2
#define SS 192
#define DD 512
#define HH 8
#define HD 64
#define QC 12            // q-rows per block in main kernel
#define PROJ_N (BB*HH*SS*HD)   // 196608 elements per projected tensor

typedef __attribute__((ext_vector_type(8))) short bf16x8;
typedef __attribute__((ext_vector_type(4))) float f32x4;

__device__ __forceinline__ unsigned short f2bf_rne(float x) {
    unsigned int u = __float_as_uint(x);
    unsigned int r = (u + 0x7FFFu + ((u >> 16) & 1u)) >> 16;
    return (unsigned short)r;
}
__device__ __forceinline__ float bf2f(unsigned short h) {
    return __uint_as_float(((unsigned int)h) << 16);
}
// split 8 f32 into hi/lo bf16 (x ~= hi + lo, error ~2^-17 rel)
__device__ __forceinline__ void split8(const float* p, bf16x8& hi, bf16x8& lo) {
#pragma unroll
    for (int i = 0; i < 8; ++i) {
        unsigned short h = f2bf_rne(p[i]);
        float rem = p[i] - bf2f(h);
        hi[i] = (short)h;
        lo[i] = (short)f2bf_rne(rem);
    }
}

// ---------------------------------------------------------------------------
// Tiled f32 GEMM body: y = x @ W^T   (x: M x 512 row-major, W: 512 x 512)
// ---------------------------------------------------------------------------
template <int SPLIT>
__device__ __forceinline__ void gemm_body(const float* __restrict__ x,
                                          const float* __restrict__ W,
                                          float* __restrict__ y) {
    __shared__ float As[32][68];
    __shared__ float Bs[32][68];

    const int t  = threadIdx.x;
    const int tx = t & 15;
    const int ty = t >> 4;
    const int m0 = blockIdx.x * 64;
    const int n0 = blockIdx.y * 64;

    float acc[4][4];
#pragma unroll
    for (int a = 0; a < 4; ++a)
#pragma unroll
        for (int b = 0; b < 4; ++b) acc[a][b] = 0.f;

    for (int kk = 0; kk < 512; kk += 32) {
#pragma unroll
        for (int r = 0; r < 2; ++r) {
            const int id  = t + r * 256;
            const int row = id >> 3;
            const int i4  = (id & 7) * 4;
            const float4 av = *reinterpret_cast<const float4*>(&x[(m0 + row) * 512 + kk + i4]);
            As[i4 + 0][row] = av.x; As[i4 + 1][row] = av.y;
            As[i4 + 2][row] = av.z; As[i4 + 3][row] = av.w;
            const float4 bv = *reinterpret_cast<const float4*>(&W[(n0 + row) * 512 + kk + i4]);
            Bs[i4 + 0][row] = bv.x; Bs[i4 + 1][row] = bv.y;
            Bs[i4 + 2][row] = bv.z; Bs[i4 + 3][row] = bv.w;
        }
        __syncthreads();
#pragma unroll
        for (int i = 0; i < 32; ++i) {
            const float4 a4 = *reinterpret_cast<const float4*>(&As[i][ty * 4]);
            const float4 b4 = *reinterpret_cast<const float4*>(&Bs[i][tx * 4]);
            const float a[4] = {a4.x, a4.y, a4.z, a4.w};
            const float b[4] = {b4.x, b4.y, b4.z, b4.w};
#pragma unroll
            for (int mi = 0; mi < 4; ++mi)
#pragma unroll
                for (int ni = 0; ni < 4; ++ni)
                    acc[mi][ni] = fmaf(a[mi], b[ni], acc[mi][ni]);
        }
        __syncthreads();
    }

#pragma unroll
    for (int mi = 0; mi < 4; ++mi) {
        const int n_row = m0 + ty * 4 + mi;
#pragma unroll
        for (int ni = 0; ni < 4; ++ni) {
            const int j = n0 + tx * 4 + ni;
            const float v = acc[mi][ni];
            if (SPLIT) {
                const int b = n_row / SS, s = n_row % SS;
                const int h = j >> 6, e = j & 63;
                y[((b * HH + h) * SS + s) * HD + e] = v;
            } else {
                y[n_row * 512 + j] = v;
            }
        }
    }
}

__global__ __launch_bounds__(256) void proj4_kernel(
    const float* __restrict__ xq, const float* __restrict__ xk,
    const float* __restrict__ xl, const float* __restrict__ xv,
    const float* __restrict__ Wq, const float* __restrict__ Wk,
    const float* __restrict__ Wv, float* __restrict__ ws) {
    const int p = blockIdx.z;
    const float* x = (p == 0) ? xq : (p == 1) ? xk : (p == 2) ? xl : xv;
    const float* W = (p == 0) ? Wq : (p == 3) ? Wv : Wk;
    float* y = ws + p * PROJ_N;
    gemm_body<1>(x, W, y);
}

__global__ __launch_bounds__(256) void outproj_kernel(
    const float* __restrict__ att, const float* __restrict__ Wout,
    float* __restrict__ out) {
    gemm_body<0>(att, Wout, out);
}

// ---------------------------------------------------------------------------
// MFMA rank-3 attention. Block = 512 thr (8 waves), grid = 256 = 16 bh x 16
// q-chunks. Per q: S^T[l,k] = L x G^T via split-bf16 mfma_f32_16x16x32_bf16,
// max-free softmax stats (sum of exp per k), attended deferred to epilogue.
// Wave w: lg = w>>2 (96 l rows), kg = w&3 (48 k cols).
// ---------------------------------------------------------------------------
__global__ __launch_bounds__(512, 2) void attn3d_mfma_kernel(
    const float* __restrict__ qh, const float* __restrict__ kh,
    const float* __restrict__ lh, const float* __restrict__ vh,
    float* __restrict__ att) {
    __shared__ float khf[8 * 192 * 8];   // [ec][k][8] f32  (48 KB)
    __shared__ short Gfh[8 * 192 * 8];   // [ec][k][8] bf16 (24 KB)
    __shared__ short Gfl[8 * 192 * 8];   // (24 KB)
    __shared__ float qs[QC][64];         // q rows, pre-scaled by 1/8
    __shared__ float partial[2][192];    // per-lg sum-exp partials
    __shared__ float Wt[QC][192];        // unnormalized per-k weights
    __shared__ float zinv[QC];

    const int blk = blockIdx.x;
    const int qc = blk & 15, bh = blk >> 4;
    const int t = threadIdx.x;
    const int lane = t & 63, w = t >> 6;
    const int lg = w >> 2, kg = w & 3;
    const int c = lane & 15, eh = lane >> 4;   // col-in-tile, e-quarter

    // ---- stage K chunk-major f32 (coalesced global reads) ----
#pragma unroll
    for (int j = 0; j < 6; ++j) {
        const int cid = t + 512 * j;          // 3072 16B quads
        const int k = cid >> 4, e4 = cid & 15;
        const f32x4 v = *reinterpret_cast<const f32x4*>(&kh[(bh * SS + k) * HD + e4 * 4]);
        *reinterpret_cast<f32x4*>(&khf[((e4 >> 1) * 192 + k) * 8 + (e4 & 1) * 4]) = v;
    }
    // ---- stage q rows (scale folded) ----
    for (int id = t; id < QC * 64; id += 512) {
        const int q = id >> 6, e = id & 63;
        qs[q][e] = qh[(bh * SS + qc * QC + q) * HD + e] * 0.125f;
    }
    // ---- A-fragments (L rows, hi/lo bf16) held in registers ----
    bf16x8 Ah[6][2], Al[6][2];
#pragma unroll
    for (int lt = 0; lt < 6; ++lt)
#pragma unroll
        for (int s = 0; s < 2; ++s) {
            const int row = lg * 96 + lt * 16 + c;
            const int e0 = 32 * s + 8 * eh;
            float buf[8];
            *reinterpret_cast<f32x4*>(&buf[0]) =
                *reinterpret_cast<const f32x4*>(&lh[(bh * SS + row) * HD + e0]);
            *reinterpret_cast<f32x4*>(&buf[4]) =
                *reinterpret_cast<const f32x4*>(&lh[(bh * SS + row) * HD + e0 + 4]);
            split8(buf, Ah[lt][s], Al[lt][s]);
        }
    __syncthreads();

    for (int q = 0; q < QC; ++q) {
        // combine previous q's partials into Wt before partials are reused
        if (q > 0 && t < 192) Wt[q - 1][t] = partial[0][t] + partial[1][t];

        // ---- G-prep: G = K o (q/8), split hi/lo, frag-major LDS ----
#pragma unroll
        for (int j = 0; j < 3; ++j) {
            const int cid = t + 512 * j;       // 1536 chunks
            const int ec = cid / 192, k = cid - ec * 192;
            const float* kp = &khf[(ec * 192 + k) * 8];
            const float* qp = &qs[q][ec * 8];
            float g[8];
#pragma unroll
            for (int i = 0; i < 8; ++i) g[i] = kp[i] * qp[i];
            bf16x8 gh, gl;
            split8(g, gh, gl);
            *reinterpret_cast<bf16x8*>(&Gfh[(ec * 192 + k) * 8]) = gh;
            *reinterpret_cast<bf16x8*>(&Gfl[(ec * 192 + k) * 8]) = gl;
        }
        __syncthreads();

        // ---- MFMA: S^T tile (96 l x 48 k per wave), 3-term split ----
        f32x4 acc[6][3];
#pragma unroll
        for (int lt = 0; lt < 6; ++lt)
#pragma unroll
            for (int kt = 0; kt < 3; ++kt) acc[lt][kt] = (f32x4){0.f, 0.f, 0.f, 0.f};

#pragma unroll
        for (int kt = 0; kt < 3; ++kt) {
            const int kcol = kg * 48 + kt * 16 + c;
#pragma unroll
            for (int s = 0; s < 2; ++s) {
                const int ec = 4 * s + eh;
                const bf16x8 Bh = *reinterpret_cast<const bf16x8*>(&Gfh[(ec * 192 + kcol) * 8]);
                const bf16x8 Bl = *reinterpret_cast<const bf16x8*>(&Gfl[(ec * 192 + kcol) * 8]);
#pragma unroll
                for (int lt = 0; lt < 6; ++lt)
                    acc[lt][kt] = __builtin_amdgcn_mfma_f32_16x16x32_bf16(Ah[lt][s], Bh, acc[lt][kt], 0, 0, 0);
#pragma unroll
                for (int lt = 0; lt < 6; ++lt)
                    acc[lt][kt] = __builtin_amdgcn_mfma_f32_16x16x32_bf16(Ah[lt][s], Bl, acc[lt][kt], 0, 0, 0);
#pragma unroll
                for (int lt = 0; lt < 6; ++lt)
                    acc[lt][kt] = __builtin_amdgcn_mfma_f32_16x16x32_bf16(Al[lt][s], Bh, acc[lt][kt], 0, 0, 0);
            }
        }

        // ---- stats: r_k = sum_l exp(s) over this wave's 96 l (max-free) ----
#pragma unroll
        for (int kt = 0; kt < 3; ++kt) {
            float r = 0.f;
#pragma unroll
            for (int lt = 0; lt < 6; ++lt)
#pragma unroll
                for (int j2 = 0; j2 < 4; ++j2) r += __expf(acc[lt][kt][j2]);
            r += __shfl_xor(r, 16, 64);
            r += __shfl_xor(r, 32, 64);
            if (eh == 0) partial[lg][kg * 48 + kt * 16 + c] = r;
        }
        __syncthreads();
    }
    if (t < 192) Wt[QC - 1][t] = partial[0][t] + partial[1][t];
    __syncthreads();

    // ---- Z per q ----
    if (t < 64) {
        for (int q = 0; q < QC; ++q) {
            float z = Wt[q][t] + Wt[q][t + 64] + Wt[q][t + 128];
#pragma unroll
            for (int off = 32; off >= 1; off >>= 1) z += __shfl_xor(z, off, 64);
            if (t == 0) zinv[q] = 1.f / z;
        }
    }
    __syncthreads();

    // ---- attended: att[q,d] = zinv * sum_k Wt[q][k] * vh[k,d] ----
    const int b = bh >> 3, h = bh & 7;
#pragma unroll
    for (int rep = 0; rep < 2; ++rep) {
        const int idx = t + 512 * rep;
        if (idx < QC * 64) {
            const int q = idx >> 6, d = idx & 63;
            const float* vp = vh + bh * SS * HD + d;
            float sum = 0.f;
#pragma unroll 4
            for (int k = 0; k < SS; ++k) sum = fmaf(Wt[q][k], vp[k * HD], sum);
            att[(b * SS + qc * QC + q) * DD + h * HD + d] = sum * zinv[q];
        }
    }
}

extern "C" void kernel_launch(void* const* d_in, const int* in_sizes, int n_in,
                              void* d_out, int out_size, void* d_ws, size_t ws_size,
                              hipStream_t stream) {
    (void)in_sizes; (void)n_in; (void)out_size; (void)ws_size;
    const float* q    = (const float*)d_in[0];
    const float* k    = (const float*)d_in[1];
    const float* l    = (const float*)d_in[2];
    const float* v    = (const float*)d_in[3];
    const float* Wq   = (const float*)d_in[4];
    const float* Wk   = (const float*)d_in[5];
    const float* Wv   = (const float*)d_in[6];
    const float* Wout = (const float*)d_in[7];
    float* out = (float*)d_out;

    float* ws  = (float*)d_ws;
    float* qhp = ws + 0 * PROJ_N;
    float* khp = ws + 1 * PROJ_N;
    float* lhp = ws + 2 * PROJ_N;
    float* vhp = ws + 3 * PROJ_N;
    float* atp = ws + 4 * PROJ_N;

    proj4_kernel<<<dim3(384 / 64, 512 / 64, 4), 256, 0, stream>>>(
        q, k, l, v, Wq, Wk, Wv, ws);
    attn3d_mfma_kernel<<<dim3(256), 512, 0, stream>>>(qhp, khp, lhp, vhp, atp);
    outproj_kernel<<<dim3(384 / 64, 512 / 64), 256, 0, stream>>>(atp, Wout, out);
}

// Round 3
// 107.699 us; speedup vs baseline: 2.5471x; 1.1845x over previous
//
#include <hip/hip_runtime.h>
#include <math.h>

#define BB 2
#define SS 192
#define DD 512
#define HH 8
#define HD 64
#define QC 12
#define PROJ_N (BB*HH*SS*HD)
#define SCL (0.125f * 1.44269504088896f)   // 1/sqrt(64) * log2(e)

typedef __attribute__((ext_vector_type(8))) short bf16x8;
typedef __attribute__((ext_vector_type(4))) float f32x4;
typedef __attribute__((ext_vector_type(4))) unsigned uint4v;

__device__ __forceinline__ unsigned cvt_pk_bf16(float a, float b) {
    unsigned r;
    asm("v_cvt_pk_bf16_f32 %0, %1, %2" : "=v"(r) : "v"(a), "v"(b));
    return r;
}
// x[0..7] ~= hi + lo (split-bf16, rel err ~2^-17)
__device__ __forceinline__ void split8_pk(const float* x, uint4v& hi, uint4v& lo) {
#pragma unroll
    for (int p = 0; p < 4; ++p) {
        const float a = x[2 * p], b = x[2 * p + 1];
        const unsigned h = cvt_pk_bf16(a, b);
        const float ra = a - __uint_as_float(h << 16);
        const float rb = b - __uint_as_float(h & 0xFFFF0000u);
        hi[p] = h;
        lo[p] = cvt_pk_bf16(ra, rb);
    }
}
__device__ __forceinline__ bf16x8 as_bf16x8(uint4v u) {
    return __builtin_bit_cast(bf16x8, u);
}

// ---------------------------------------------------------------------------
// Split-bf16 MFMA GEMM: y = x @ W^T   (x: M x 512, W: 512 x 512, f32)
// 64x64 tile / block, 256 thr (4 waves, 2x2), BK=32, double-buffered LDS.
// 3-term split: AhBh + AhBl + AlBh  (drops only AlBl ~ 2^-16 rel).
// ---------------------------------------------------------------------------
template <int SPLIT>
__device__ __forceinline__ void gemm_mfma_body(const float* __restrict__ x,
                                               const float* __restrict__ W,
                                               float* __restrict__ y) {
    __shared__ short Ahs[2][4 * 64 * 8], Als[2][4 * 64 * 8];  // [buf][c][row][8]
    __shared__ short Bhs[2][4 * 64 * 8], Bls[2][4 * 64 * 8];

    const int t = threadIdx.x;
    const int lane = t & 63, w = t >> 6;
    const int wr = w >> 1, wc = w & 1;
    const int c16 = lane & 15, q4 = lane >> 4;
    const int m0 = blockIdx.x * 64, n0 = blockIdx.y * 64;
    const int sr = t >> 2, scc = t & 3;   // staging: row 0..63, k-chunk 0..3

    f32x4 acc[2][2];
#pragma unroll
    for (int a = 0; a < 2; ++a)
#pragma unroll
        for (int b = 0; b < 2; ++b) acc[a][b] = (f32x4){0.f, 0.f, 0.f, 0.f};

#define STAGE(kk, bf)                                                              \
    {                                                                              \
        float a8[8], w8[8];                                                        \
        *(f32x4*)&a8[0] = *(const f32x4*)&x[(m0 + sr) * 512 + (kk) + scc * 8];     \
        *(f32x4*)&a8[4] = *(const f32x4*)&x[(m0 + sr) * 512 + (kk) + scc * 8 + 4]; \
        *(f32x4*)&w8[0] = *(const f32x4*)&W[(n0 + sr) * 512 + (kk) + scc * 8];     \
        *(f32x4*)&w8[4] = *(const f32x4*)&W[(n0 + sr) * 512 + (kk) + scc * 8 + 4]; \
        uint4v h, l;                                                               \
        split8_pk(a8, h, l);                                                       \
        *(uint4v*)&Ahs[bf][(scc * 64 + sr) * 8] = h;                               \
        *(uint4v*)&Als[bf][(scc * 64 + sr) * 8] = l;                               \
        split8_pk(w8, h, l);                                                       \
        *(uint4v*)&Bhs[bf][(scc * 64 + sr) * 8] = h;                               \
        *(uint4v*)&Bls[bf][(scc * 64 + sr) * 8] = l;                               \
    }

    STAGE(0, 0)
    for (int s = 0; s < 16; ++s) {
        __syncthreads();
        if (s + 1 < 16) STAGE((s + 1) * 32, (s + 1) & 1)
        const int b = s & 1;
        bf16x8 aH[2], aL[2], bH[2], bL[2];
#pragma unroll
        for (int mt = 0; mt < 2; ++mt) {
            const int row = wr * 32 + mt * 16 + c16;
            aH[mt] = *(const bf16x8*)&Ahs[b][(q4 * 64 + row) * 8];
            aL[mt] = *(const bf16x8*)&Als[b][(q4 * 64 + row) * 8];
        }
#pragma unroll
        for (int nt = 0; nt < 2; ++nt) {
            const int col = wc * 32 + nt * 16 + c16;
            bH[nt] = *(const bf16x8*)&Bhs[b][(q4 * 64 + col) * 8];
            bL[nt] = *(const bf16x8*)&Bls[b][(q4 * 64 + col) * 8];
        }
#pragma unroll
        for (int mt = 0; mt < 2; ++mt)
#pragma unroll
            for (int nt = 0; nt < 2; ++nt) {
                acc[mt][nt] = __builtin_amdgcn_mfma_f32_16x16x32_bf16(aH[mt], bH[nt], acc[mt][nt], 0, 0, 0);
                acc[mt][nt] = __builtin_amdgcn_mfma_f32_16x16x32_bf16(aH[mt], bL[nt], acc[mt][nt], 0, 0, 0);
                acc[mt][nt] = __builtin_amdgcn_mfma_f32_16x16x32_bf16(aL[mt], bH[nt], acc[mt][nt], 0, 0, 0);
            }
    }
#undef STAGE

#pragma unroll
    for (int mt = 0; mt < 2; ++mt)
#pragma unroll
        for (int nt = 0; nt < 2; ++nt)
#pragma unroll
            for (int j = 0; j < 4; ++j) {
                const int n_row = m0 + wr * 32 + mt * 16 + q4 * 4 + j;
                const int col = n0 + wc * 32 + nt * 16 + c16;
                const float v = acc[mt][nt][j];
                if (SPLIT) {
                    const int b = n_row / SS, s2 = n_row % SS;
                    const int h = col >> 6, e = col & 63;
                    y[((b * HH + h) * SS + s2) * HD + e] = v;
                } else {
                    y[n_row * 512 + col] = v;
                }
            }
}

__global__ __launch_bounds__(256) void proj4_kernel(
    const float* __restrict__ xq, const float* __restrict__ xk,
    const float* __restrict__ xl, const float* __restrict__ xv,
    const float* __restrict__ Wq, const float* __restrict__ Wk,
    const float* __restrict__ Wv, float* __restrict__ ws) {
    const int p = blockIdx.z;
    const float* x = (p == 0) ? xq : (p == 1) ? xk : (p == 2) ? xl : xv;
    const float* W = (p == 0) ? Wq : (p == 3) ? Wv : Wk;
    gemm_mfma_body<1>(x, W, ws + p * PROJ_N);
}

__global__ __launch_bounds__(256) void outproj_kernel(
    const float* __restrict__ att, const float* __restrict__ Wout,
    float* __restrict__ out) {
    gemm_mfma_body<0>(att, Wout, out);
}

// ---------------------------------------------------------------------------
// MFMA rank-3 attention, software-pipelined.
// Grid 256 = 16 bh x 16 q-chunks; 512 thr (8 waves: 2 lg x 4 kg).
// Per q: S^T[l,k] = L x G^T (G = q*K) via 3-term split-bf16 MFMA; max-free
// sum-exp per k (exp2, log2e pre-folded); G double-buffered so prep(q+1)
// overlaps MFMA(q)+stats(q). K held in registers (addresses q-invariant).
// ---------------------------------------------------------------------------
__global__ __launch_bounds__(512) void attn3d_mfma_kernel(
    const float* __restrict__ qh, const float* __restrict__ kh,
    const float* __restrict__ lh, const float* __restrict__ vh,
    float* __restrict__ att) {
    __shared__ short Gfh[2][8 * 192 * 8];   // [buf][ec][k][8] bf16 hi (48 KB)
    __shared__ short Gfl[2][8 * 192 * 8];   // lo (48 KB)
    __shared__ float qs[QC][64];            // q rows, SCL folded
    __shared__ float partial[2][2][192];    // [qbuf][lg][k]
    __shared__ float Wt[QC][192];
    __shared__ float zinv[QC];

    const int blk = blockIdx.x;
    const int qc = blk & 15, bh = blk >> 4;
    const int t = threadIdx.x;
    const int lane = t & 63, w = t >> 6;
    const int lg = w >> 2, kg = w & 3;
    const int c = lane & 15, eh = lane >> 4;

    // per-thread G-chunk meta (fixed across q) + K in registers
    int ecj[3], kj[3];
    float Kreg[3][8];
#pragma unroll
    for (int j = 0; j < 3; ++j) {
        const int cid = t + 512 * j;
        ecj[j] = cid / 192;
        kj[j] = cid - ecj[j] * 192;
        const float* kp = &kh[(bh * SS + kj[j]) * HD + ecj[j] * 8];
        *(f32x4*)&Kreg[j][0] = *(const f32x4*)&kp[0];
        *(f32x4*)&Kreg[j][4] = *(const f32x4*)&kp[4];
    }
    // stage q rows (scale+log2e folded)
    for (int id = t; id < QC * 64; id += 512) {
        const int q = id >> 6, e = id & 63;
        qs[q][e] = qh[(bh * SS + qc * QC + q) * HD + e] * SCL;
    }
    // A-fragments: L rows split hi/lo, held in registers
    bf16x8 Ah[6][2], Al[6][2];
#pragma unroll
    for (int lt = 0; lt < 6; ++lt)
#pragma unroll
        for (int s = 0; s < 2; ++s) {
            const int row = lg * 96 + lt * 16 + c;
            const int e0 = 32 * s + 8 * eh;
            float buf8[8];
            *(f32x4*)&buf8[0] = *(const f32x4*)&lh[(bh * SS + row) * HD + e0];
            *(f32x4*)&buf8[4] = *(const f32x4*)&lh[(bh * SS + row) * HD + e0 + 4];
            uint4v h, l;
            split8_pk(buf8, h, l);
            Ah[lt][s] = as_bf16x8(h);
            Al[lt][s] = as_bf16x8(l);
        }
    __syncthreads();   // qs ready

#define PREP(qq, bf)                                                    \
    {                                                                   \
        _Pragma("unroll") for (int j = 0; j < 3; ++j) {                 \
            float g8[8];                                                \
            const float* qp = &qs[qq][ecj[j] * 8];                      \
            _Pragma("unroll") for (int i = 0; i < 8; ++i)               \
                g8[i] = Kreg[j][i] * qp[i];                             \
            uint4v h, l;                                                \
            split8_pk(g8, h, l);                                        \
            const int off = (ecj[j] * 192 + kj[j]) * 8;                 \
            *(uint4v*)&Gfh[bf][off] = h;                                \
            *(uint4v*)&Gfl[bf][off] = l;                                \
        }                                                               \
    }

    PREP(0, 0)

    for (int q = 0; q < QC; ++q) {
        __syncthreads();   // Gf(q) ready; partial(q-1) ready
        if (q > 0 && t < 192)
            Wt[q - 1][t] = partial[(q - 1) & 1][0][t] + partial[(q - 1) & 1][1][t];

        const int buf = q & 1;
        f32x4 acc[6][3];
#pragma unroll
        for (int lt = 0; lt < 6; ++lt)
#pragma unroll
            for (int kt = 0; kt < 3; ++kt) acc[lt][kt] = (f32x4){0.f, 0.f, 0.f, 0.f};

#pragma unroll
        for (int kt = 0; kt < 3; ++kt) {
            const int kcol = kg * 48 + kt * 16 + c;
#pragma unroll
            for (int s = 0; s < 2; ++s) {
                const int ec = 4 * s + eh;
                const bf16x8 Bh = *(const bf16x8*)&Gfh[buf][(ec * 192 + kcol) * 8];
                const bf16x8 Bl = *(const bf16x8*)&Gfl[buf][(ec * 192 + kcol) * 8];
#pragma unroll
                for (int lt = 0; lt < 6; ++lt)
                    acc[lt][kt] = __builtin_amdgcn_mfma_f32_16x16x32_bf16(Ah[lt][s], Bh, acc[lt][kt], 0, 0, 0);
#pragma unroll
                for (int lt = 0; lt < 6; ++lt)
                    acc[lt][kt] = __builtin_amdgcn_mfma_f32_16x16x32_bf16(Ah[lt][s], Bl, acc[lt][kt], 0, 0, 0);
#pragma unroll
                for (int lt = 0; lt < 6; ++lt)
                    acc[lt][kt] = __builtin_amdgcn_mfma_f32_16x16x32_bf16(Al[lt][s], Bh, acc[lt][kt], 0, 0, 0);
            }
        }

        // prep next q's G into the other buffer (overlaps MFMA/stats)
        if (q + 1 < QC) PREP(q + 1, buf ^ 1)

        // stats: r_k = sum_l exp2(s') over this wave's 96 l rows
#pragma unroll
        for (int kt = 0; kt < 3; ++kt) {
            float r = 0.f;
#pragma unroll
            for (int lt = 0; lt < 6; ++lt)
#pragma unroll
                for (int j2 = 0; j2 < 4; ++j2) r += exp2f(acc[lt][kt][j2]);
            r += __shfl_xor(r, 16, 64);
            r += __shfl_xor(r, 32, 64);
            if (eh == 0) partial[buf][lg][kg * 48 + kt * 16 + c] = r;
        }
    }
#undef PREP
    __syncthreads();
    if (t < 192)
        Wt[QC - 1][t] = partial[(QC - 1) & 1][0][t] + partial[(QC - 1) & 1][1][t];
    __syncthreads();

    // Z per q
    if (t < 64) {
        for (int q = 0; q < QC; ++q) {
            float z = Wt[q][t] + Wt[q][t + 64] + Wt[q][t + 128];
#pragma unroll
            for (int off = 32; off >= 1; off >>= 1) z += __shfl_xor(z, off, 64);
            if (t == 0) zinv[q] = 1.f / z;
        }
    }
    __syncthreads();

    // attended: att[q,d] = zinv * sum_k Wt[q][k] * vh[k,d]
    const int b = bh >> 3, h = bh & 7;
#pragma unroll
    for (int rep = 0; rep < 2; ++rep) {
        const int idx = t + 512 * rep;
        if (idx < QC * 64) {
            const int q = idx >> 6, d = idx & 63;
            const float* vp = vh + bh * SS * HD + d;
            float sum = 0.f;
#pragma unroll 4
            for (int k = 0; k < SS; ++k) sum = fmaf(Wt[q][k], vp[k * HD], sum);
            att[(b * SS + qc * QC + q) * DD + h * HD + d] = sum * zinv[q];
        }
    }
}

extern "C" void kernel_launch(void* const* d_in, const int* in_sizes, int n_in,
                              void* d_out, int out_size, void* d_ws, size_t ws_size,
                              hipStream_t stream) {
    (void)in_sizes; (void)n_in; (void)out_size; (void)ws_size;
    const float* q    = (const float*)d_in[0];
    const float* k    = (const float*)d_in[1];
    const float* l    = (const float*)d_in[2];
    const float* v    = (const float*)d_in[3];
    const float* Wq   = (const float*)d_in[4];
    const float* Wk   = (const float*)d_in[5];
    const float* Wv   = (const float*)d_in[6];
    const float* Wout = (const float*)d_in[7];
    float* out = (float*)d_out;

    float* ws  = (float*)d_ws;
    float* qhp = ws + 0 * PROJ_N;
    float* khp = ws + 1 * PROJ_N;
    float* lhp = ws + 2 * PROJ_N;
    float* vhp = ws + 3 * PROJ_N;
    float* atp = ws + 4 * PROJ_N;

    proj4_kernel<<<dim3(384 / 64, 512 / 64, 4), 256, 0, stream>>>(
        q, k, l, v, Wq, Wk, Wv, ws);
    attn3d_mfma_kernel<<<dim3(256), 512, 0, stream>>>(qhp, khp, lhp, vhp, atp);
    outproj_kernel<<<dim3(384 / 64, 512 / 64), 256, 0, stream>>>(atp, Wout, out);
}

// Round 5
// 89.691 us; speedup vs baseline: 3.0585x; 1.2008x over previous
//
#include <hip/hip_runtime.h>
#include <math.h>

#define BB 2
#define SS 192
#define DD 512
#define HH 8
#define HD 64
#define QC 12
#define PROJ_N (BB*HH*SS*HD)
#define SCL (0.125f * 1.44269504088896f)   // 1/sqrt(64) * log2(e)

typedef __attribute__((ext_vector_type(8))) short bf16x8;
typedef __attribute__((ext_vector_type(4))) float f32x4;
typedef __attribute__((ext_vector_type(4))) unsigned uint4v;
typedef _Float16 f16x8 __attribute__((ext_vector_type(8)));

__device__ __forceinline__ unsigned cvt_pk_bf16(float a, float b) {
    unsigned r;
    asm("v_cvt_pk_bf16_f32 %0, %1, %2" : "=v"(r) : "v"(a), "v"(b));
    return r;
}
// x[0..7] ~= hi + lo (split-bf16, rel err ~2^-17) -- used by projection GEMMs
__device__ __forceinline__ void split8_pk(const float* x, uint4v& hi, uint4v& lo) {
#pragma unroll
    for (int p = 0; p < 4; ++p) {
        const float a = x[2 * p], b = x[2 * p + 1];
        const unsigned h = cvt_pk_bf16(a, b);
        const float ra = a - __uint_as_float(h << 16);
        const float rb = b - __uint_as_float(h & 0xFFFF0000u);
        hi[p] = h;
        lo[p] = cvt_pk_bf16(ra, rb);
    }
}

// pack 8 f32 -> f16x8 via v_cvt_pkrtz_f16_f32 (hot path)
__device__ __forceinline__ f16x8 pack8_f16(const float* g) {
    uint4v u;
#pragma unroll
    for (int p = 0; p < 4; ++p)
        u[p] = __builtin_bit_cast(unsigned,
                                  __builtin_amdgcn_cvt_pkrtz(g[2 * p], g[2 * p + 1]));
    return __builtin_bit_cast(f16x8, u);
}

// ---------------------------------------------------------------------------
// Split-bf16 MFMA GEMM: y = x @ W^T   (x: M x 512, W: 512 x 512, f32)
// 64x64 tile / block, 256 thr (4 waves, 2x2), BK=32, double-buffered LDS.
// ---------------------------------------------------------------------------
template <int SPLIT>
__device__ __forceinline__ void gemm_mfma_body(const float* __restrict__ x,
                                               const float* __restrict__ W,
                                               float* __restrict__ y) {
    __shared__ short Ahs[2][4 * 64 * 8], Als[2][4 * 64 * 8];
    __shared__ short Bhs[2][4 * 64 * 8], Bls[2][4 * 64 * 8];

    const int t = threadIdx.x;
    const int lane = t & 63, w = t >> 6;
    const int wr = w >> 1, wc = w & 1;
    const int c16 = lane & 15, q4 = lane >> 4;
    const int m0 = blockIdx.x * 64, n0 = blockIdx.y * 64;
    const int sr = t >> 2, scc = t & 3;

    f32x4 acc[2][2];
#pragma unroll
    for (int a = 0; a < 2; ++a)
#pragma unroll
        for (int b = 0; b < 2; ++b) acc[a][b] = (f32x4){0.f, 0.f, 0.f, 0.f};

#define STAGE(kk, bf)                                                              \
    {                                                                              \
        float a8[8], w8[8];                                                        \
        *(f32x4*)&a8[0] = *(const f32x4*)&x[(m0 + sr) * 512 + (kk) + scc * 8];     \
        *(f32x4*)&a8[4] = *(const f32x4*)&x[(m0 + sr) * 512 + (kk) + scc * 8 + 4]; \
        *(f32x4*)&w8[0] = *(const f32x4*)&W[(n0 + sr) * 512 + (kk) + scc * 8];     \
        *(f32x4*)&w8[4] = *(const f32x4*)&W[(n0 + sr) * 512 + (kk) + scc * 8 + 4]; \
        uint4v h, l;                                                               \
        split8_pk(a8, h, l);                                                       \
        *(uint4v*)&Ahs[bf][(scc * 64 + sr) * 8] = h;                               \
        *(uint4v*)&Als[bf][(scc * 64 + sr) * 8] = l;                               \
        split8_pk(w8, h, l);                                                       \
        *(uint4v*)&Bhs[bf][(scc * 64 + sr) * 8] = h;                               \
        *(uint4v*)&Bls[bf][(scc * 64 + sr) * 8] = l;                               \
    }

    STAGE(0, 0)
    for (int s = 0; s < 16; ++s) {
        __syncthreads();
        if (s + 1 < 16) STAGE((s + 1) * 32, (s + 1) & 1)
        const int b = s & 1;
        bf16x8 aH[2], aL[2], bH[2], bL[2];
#pragma unroll
        for (int mt = 0; mt < 2; ++mt) {
            const int row = wr * 32 + mt * 16 + c16;
            aH[mt] = *(const bf16x8*)&Ahs[b][(q4 * 64 + row) * 8];
            aL[mt] = *(const bf16x8*)&Als[b][(q4 * 64 + row) * 8];
        }
#pragma unroll
        for (int nt = 0; nt < 2; ++nt) {
            const int col = wc * 32 + nt * 16 + c16;
            bH[nt] = *(const bf16x8*)&Bhs[b][(q4 * 64 + col) * 8];
            bL[nt] = *(const bf16x8*)&Bls[b][(q4 * 64 + col) * 8];
        }
#pragma unroll
        for (int mt = 0; mt < 2; ++mt)
#pragma unroll
            for (int nt = 0; nt < 2; ++nt) {
                acc[mt][nt] = __builtin_amdgcn_mfma_f32_16x16x32_bf16(aH[mt], bH[nt], acc[mt][nt], 0, 0, 0);
                acc[mt][nt] = __builtin_amdgcn_mfma_f32_16x16x32_bf16(aH[mt], bL[nt], acc[mt][nt], 0, 0, 0);
                acc[mt][nt] = __builtin_amdgcn_mfma_f32_16x16x32_bf16(aL[mt], bH[nt], acc[mt][nt], 0, 0, 0);
            }
    }
#undef STAGE

#pragma unroll
    for (int mt = 0; mt < 2; ++mt)
#pragma unroll
        for (int nt = 0; nt < 2; ++nt)
#pragma unroll
            for (int j = 0; j < 4; ++j) {
                const int n_row = m0 + wr * 32 + mt * 16 + q4 * 4 + j;
                const int col = n0 + wc * 32 + nt * 16 + c16;
                const float v = acc[mt][nt][j];
                if (SPLIT) {
                    const int b = n_row / SS, s2 = n_row % SS;
                    const int h = col >> 6, e = col & 63;
                    y[((b * HH + h) * SS + s2) * HD + e] = v;
                } else {
                    y[n_row * 512 + col] = v;
                }
            }
}

__global__ __launch_bounds__(256) void proj4_kernel(
    const float* __restrict__ xq, const float* __restrict__ xk,
    const float* __restrict__ xl, const float* __restrict__ xv,
    const float* __restrict__ Wq, const float* __restrict__ Wk,
    const float* __restrict__ Wv, float* __restrict__ ws) {
    const int p = blockIdx.z;
    const float* x = (p == 0) ? xq : (p == 1) ? xk : (p == 2) ? xl : xv;
    const float* W = (p == 0) ? Wq : (p == 3) ? Wv : Wk;
    gemm_mfma_body<1>(x, W, ws + p * PROJ_N);
}

__global__ __launch_bounds__(256) void outproj_kernel(
    const float* __restrict__ att, const float* __restrict__ Wout,
    float* __restrict__ out) {
    gemm_mfma_body<0>(att, Wout, out);
}

// ---------------------------------------------------------------------------
// Barrier-free MFMA rank-3 attention.
// Grid 256 = 16 bh x 16 qc (QC=12). 512 thr = 8 waves (2 lg x 4 kg).
// A = L rows (f16, regs, q-invariant). B = G = K*q built per-lane in regs
// from a K register slice (48 VGPR) x 8 broadcast q-values. No LDS, no
// barriers in the q loop; stats -> partial LDS; single barrier at the end.
// ---------------------------------------------------------------------------
__global__ __launch_bounds__(512) void attn3d_mfma_kernel(
    const float* __restrict__ qh, const float* __restrict__ kh,
    const float* __restrict__ lh, const float* __restrict__ vh,
    float* __restrict__ att) {
    __shared__ float qs[QC][64];          // q rows, SCL folded (3 KB)
    __shared__ float partial[2][QC][192]; // per-lg sum-exp partials (18 KB)
    __shared__ float Wt[QC][192];         // combined weights (9 KB)
    __shared__ float zinv[QC];

    const int blk = blockIdx.x;
    const int qc = blk & 15, bh = blk >> 4;
    const int t = threadIdx.x;
    const int lane = t & 63, w = t >> 6;
    const int lg = w >> 2, kg = w & 3;
    const int c = lane & 15, eh = lane >> 4;

    // stage q rows (scale+log2e folded)
    for (int id = t; id < QC * 64; id += 512) {
        const int q = id >> 6, e = id & 63;
        qs[q][e] = qh[(bh * SS + qc * QC + q) * HD + e] * SCL;
    }

    // K slice in registers: Kreg[kt][s][8] for col = kg*48+kt*16+c, e = s*32+eh*8..
    float Kreg[3][2][8];
#pragma unroll
    for (int kt = 0; kt < 3; ++kt)
#pragma unroll
        for (int s = 0; s < 2; ++s) {
            const int col = kg * 48 + kt * 16 + c;
            const float* kp = &kh[(bh * SS + col) * HD + s * 32 + eh * 8];
            *(f32x4*)&Kreg[kt][s][0] = *(const f32x4*)&kp[0];
            *(f32x4*)&Kreg[kt][s][4] = *(const f32x4*)&kp[4];
        }

    // A fragments: L rows as single f16 (RTZ pack), q-invariant
    f16x8 Af[6][2];
#pragma unroll
    for (int lt = 0; lt < 6; ++lt)
#pragma unroll
        for (int s = 0; s < 2; ++s) {
            const int row = lg * 96 + lt * 16 + c;
            float buf8[8];
            const float* lp = &lh[(bh * SS + row) * HD + s * 32 + eh * 8];
            *(f32x4*)&buf8[0] = *(const f32x4*)&lp[0];
            *(f32x4*)&buf8[4] = *(const f32x4*)&lp[4];
            Af[lt][s] = pack8_f16(buf8);
        }
    __syncthreads();   // qs ready

    // ---- barrier-free q loop ----
    for (int q = 0; q < QC; ++q) {
        float qv[2][8];
#pragma unroll
        for (int s = 0; s < 2; ++s) {
            *(f32x4*)&qv[s][0] = *(const f32x4*)&qs[q][s * 32 + eh * 8];
            *(f32x4*)&qv[s][4] = *(const f32x4*)&qs[q][s * 32 + eh * 8 + 4];
        }
#pragma unroll
        for (int kt = 0; kt < 3; ++kt) {
            // B = (K*q) as single f16, built in-register
            f16x8 Bf[2];
#pragma unroll
            for (int s = 0; s < 2; ++s) {
                float g8[8];
#pragma unroll
                for (int i = 0; i < 8; ++i) g8[i] = Kreg[kt][s][i] * qv[s][i];
                Bf[s] = pack8_f16(g8);
            }
            f32x4 acc[6];
#pragma unroll
            for (int lt = 0; lt < 6; ++lt) acc[lt] = (f32x4){0.f, 0.f, 0.f, 0.f};
#pragma unroll
            for (int lt = 0; lt < 6; ++lt) {
                acc[lt] = __builtin_amdgcn_mfma_f32_16x16x32_f16(Af[lt][0], Bf[0], acc[lt], 0, 0, 0);
                acc[lt] = __builtin_amdgcn_mfma_f32_16x16x32_f16(Af[lt][1], Bf[1], acc[lt], 0, 0, 0);
            }
            // r_k = sum over this wave's 96 l rows of exp2(score)
            float r0 = 0.f, r1 = 0.f, r2 = 0.f, r3 = 0.f;
#pragma unroll
            for (int lt = 0; lt < 6; ++lt) {
                r0 += exp2f(acc[lt][0]);
                r1 += exp2f(acc[lt][1]);
                r2 += exp2f(acc[lt][2]);
                r3 += exp2f(acc[lt][3]);
            }
            float r = (r0 + r1) + (r2 + r3);
            r += __shfl_xor(r, 16, 64);
            r += __shfl_xor(r, 32, 64);
            if (eh == 0) partial[lg][q][kg * 48 + kt * 16 + c] = r;
        }
    }
    __syncthreads();   // all partials written

    // combine lg partials
    for (int id = t; id < QC * 192; id += 512) {
        const int q = id / 192, k = id - q * 192;
        Wt[q][k] = partial[0][q][k] + partial[1][q][k];
    }
    __syncthreads();

    // Z per q (wave-parallel: wave w handles q = w, q = w+8)
#pragma unroll
    for (int rr = 0; rr < 2; ++rr) {
        const int q = w + rr * 8;
        if (q < QC) {
            float z = Wt[q][lane] + Wt[q][lane + 64] + Wt[q][lane + 128];
#pragma unroll
            for (int off = 32; off >= 1; off >>= 1) z += __shfl_xor(z, off, 64);
            if (lane == 0) zinv[q] = 1.f / z;
        }
    }
    __syncthreads();

    // attended: att[q,d] = zinv * sum_k Wt[q][k] * vh[k,d]
    const int b = bh >> 3, h = bh & 7;
#pragma unroll
    for (int rep = 0; rep < 2; ++rep) {
        const int idx = t + 512 * rep;
        if (idx < QC * 64) {
            const int q = idx >> 6, d = idx & 63;
            const float* vp = vh + bh * SS * HD + d;
            float sum = 0.f;
#pragma unroll 4
            for (int k = 0; k < SS; ++k) sum = fmaf(Wt[q][k], vp[k * HD], sum);
            att[(b * SS + qc * QC + q) * DD + h * HD + d] = sum * zinv[q];
        }
    }
}

extern "C" void kernel_launch(void* const* d_in, const int* in_sizes, int n_in,
                              void* d_out, int out_size, void* d_ws, size_t ws_size,
                              hipStream_t stream) {
    (void)in_sizes; (void)n_in; (void)out_size; (void)ws_size;
    const float* q    = (const float*)d_in[0];
    const float* k    = (const float*)d_in[1];
    const float* l    = (const float*)d_in[2];
    const float* v    = (const float*)d_in[3];
    const float* Wq   = (const float*)d_in[4];
    const float* Wk   = (const float*)d_in[5];
    const float* Wv   = (const float*)d_in[6];
    const float* Wout = (const float*)d_in[7];
    float* out = (float*)d_out;

    float* ws  = (float*)d_ws;
    float* qhp = ws + 0 * PROJ_N;
    float* khp = ws + 1 * PROJ_N;
    float* lhp = ws + 2 * PROJ_N;
    float* vhp = ws + 3 * PROJ_N;
    float* atp = ws + 4 * PROJ_N;

    proj4_kernel<<<dim3(384 / 64, 512 / 64, 4), 256, 0, stream>>>(
        q, k, l, v, Wq, Wk, Wv, ws);
    attn3d_mfma_kernel<<<dim3(256), 512, 0, stream>>>(qhp, khp, lhp, vhp, atp);
    outproj_kernel<<<dim3(384 / 64, 512 / 64), 256, 0, stream>>>(atp, Wout, out);
}